// Round 6
// baseline (456.205 us; speedup 1.0000x reference)
//
#include <hip/hip_runtime.h>
#include <math.h>

#define CH 4096        // edges per partition block
#define NBUK_MAX 256   // max buckets (N <= 131072)
#define MAXB 12288     // max edges per bucket staged in LDS (48 KB)
#define SRC_BITS 17    // N < 131072 fits in 17 bits

// ---------------- P1a: per-block bucket histograms (dst-bucket and src-bucket) ----------------
__global__ __launch_bounds__(256) void p1a_kernel(const int* __restrict__ src, const int* __restrict__ dst,
                                                  int* __restrict__ mat, int E, int B1, int nbuk) {
    __shared__ int hd[NBUK_MAX], hs[NBUK_MAX];
    const int t = threadIdx.x;
    if (t < nbuk) { hd[t] = 0; hs[t] = 0; }
    __syncthreads();
    const int base = blockIdx.x * CH;
    const int cnt = min(CH, E - base);
    for (int k = t; k < cnt; k += 256) {
        int d = dst[base + k];
        int s = src[base + k];
        atomicAdd(&hd[d >> 9], 1);
        atomicAdd(&hs[s >> 9], 1);
    }
    __syncthreads();
    if (t < nbuk) {
        mat[t * B1 + blockIdx.x] = hd[t];
        mat[(nbuk + t) * B1 + blockIdx.x] = hs[t];
    }
}

// ---------------- 3-phase exclusive scan ----------------
__global__ __launch_bounds__(256) void scan1_kernel(const int* __restrict__ cnt,
                                                    int* __restrict__ seg,
                                                    int* __restrict__ bsums, int N) {
    __shared__ int tsum[256];
    const int t = threadIdx.x;
    const int base = blockIdx.x * 1024 + t * 4;
    int v0 = (base + 0 < N) ? cnt[base + 0] : 0;
    int v1 = (base + 1 < N) ? cnt[base + 1] : 0;
    int v2 = (base + 2 < N) ? cnt[base + 2] : 0;
    int v3 = (base + 3 < N) ? cnt[base + 3] : 0;
    tsum[t] = v0 + v1 + v2 + v3;
    __syncthreads();
    for (int off = 1; off < 256; off <<= 1) {
        int x = (t >= off) ? tsum[t - off] : 0;
        __syncthreads();
        if (t >= off) tsum[t] += x;
        __syncthreads();
    }
    int run = (t > 0) ? tsum[t - 1] : 0;
    if (base + 0 < N) seg[base + 0] = run; run += v0;
    if (base + 1 < N) seg[base + 1] = run; run += v1;
    if (base + 2 < N) seg[base + 2] = run; run += v2;
    if (base + 3 < N) seg[base + 3] = run;
    if (t == 255) bsums[blockIdx.x] = tsum[255];
}

__global__ void scan2_kernel(int* __restrict__ bsums, int* __restrict__ seg, int N, int G) {
    __shared__ int s[256];
    int t = threadIdx.x;
    if (t < G) s[t] = bsums[t];
    __syncthreads();
    if (t == 0) {
        int run = 0;
        for (int i = 0; i < G; ++i) { int v = s[i]; s[i] = run; run += v; }
        seg[N] = run;
    }
    __syncthreads();
    if (t < G) bsums[t] = s[t];
}

__global__ __launch_bounds__(256) void scan3_kernel(int* __restrict__ seg,
                                                    const int* __restrict__ bsums, int N) {
    int add = bsums[blockIdx.x];
    int base = blockIdx.x * 1024 + threadIdx.x * 4;
#pragma unroll
    for (int i = 0; i < 4; ++i) {
        int idx = base + i;
        if (idx < N) seg[idx] += add;
    }
}

// ---------------- P1c: LDS-staged partition scatter ----------------
// pedge[0..E): dst-partitioned packed ((dst&511)<<17)|src
// pedge[E..2E): src-partitioned raw src (scan's src-region offsets land here)
__global__ __launch_bounds__(256) void p1c_kernel(const int* __restrict__ src, const int* __restrict__ dst,
                                                  const int* __restrict__ scan,
                                                  int* __restrict__ pedge,
                                                  int E, int B1, int nbuk) {
    __shared__ int hd[NBUK_MAX], hs[NBUK_MAX];
    __shared__ int curD[NBUK_MAX], curS[NBUK_MAX];
    __shared__ int baseD[NBUK_MAX], baseS[NBUK_MAX];
    __shared__ int stD[CH];   // packed
    __shared__ int stS[CH];   // src only
    const int t = threadIdx.x;
    if (t < nbuk) { hd[t] = 0; hs[t] = 0; }
    __syncthreads();
    const int base = blockIdx.x * CH;
    const int cnt = min(CH, E - base);
    int dl[CH / 256], sl[CH / 256];
#pragma unroll
    for (int k = 0; k < CH / 256; ++k) {
        int i = t + k * 256;
        if (i < cnt) {
            dl[k] = dst[base + i];
            sl[k] = src[base + i];
            atomicAdd(&hd[dl[k] >> 9], 1);
            atomicAdd(&hs[sl[k] >> 9], 1);
        }
    }
    __syncthreads();
    for (int off = 1; off < nbuk; off <<= 1) {
        int v0 = (t >= off && t < nbuk) ? hd[t - off] : 0;
        int w0 = (t >= off && t < nbuk) ? hs[t - off] : 0;
        __syncthreads();
        if (t < nbuk) { hd[t] += v0; hs[t] += w0; }
        __syncthreads();
    }
    if (t < nbuk) {
        int excD = t ? hd[t - 1] : 0;
        int excS = t ? hs[t - 1] : 0;
        curD[t] = excD;
        curS[t] = excS;
        baseD[t] = scan[t * B1 + blockIdx.x] - excD;
        baseS[t] = scan[(nbuk + t) * B1 + blockIdx.x] - excS;
    }
    __syncthreads();
#pragma unroll
    for (int k = 0; k < CH / 256; ++k) {
        int i = t + k * 256;
        if (i < cnt) {
            int j = dl[k] >> 9;
            int p = atomicAdd(&curD[j], 1);
            stD[p] = ((dl[k] & 511) << SRC_BITS) | sl[k];
            int jq = sl[k] >> 9;
            int q = atomicAdd(&curS[jq], 1);
            stS[q] = sl[k];
        }
    }
    __syncthreads();
    for (int i = t; i < cnt; i += 256) {
        int lo = 0, hi = nbuk - 1;
        while (lo < hi) { int mid = (lo + hi) >> 1; if (hd[mid] > i) hi = mid; else lo = mid + 1; }
        pedge[baseD[lo] + i] = stD[i];
        int lo2 = 0, hi2 = nbuk - 1;
        while (lo2 < hi2) { int mid = (lo2 + hi2) >> 1; if (hs[mid] > i) hi2 = mid; else lo2 = mid + 1; }
        pedge[baseS[lo2] + i] = stS[i];
    }
}

// ---------------- P2: per-bucket local sort -> esrc (coalesced), seg, norm_dst ----------------
__global__ __launch_bounds__(256) void p2_kernel(const int* __restrict__ pedge,
                                                 const int* __restrict__ scan,
                                                 int* __restrict__ esrc, int* __restrict__ seg,
                                                 float* __restrict__ norm_dst,
                                                 int N, int E, int B1) {
    __shared__ int h[512];
    __shared__ int cur[512];
    __shared__ int stage[MAXB];
    const int t = threadIdx.x;
    const int b = blockIdx.x;
    h[t] = 0; h[t + 256] = 0;
    __syncthreads();
    const int bb0 = scan[b * B1];
    const int bb1 = scan[(b + 1) * B1];
    for (int i = bb0 + t; i < bb1; i += 256) atomicAdd(&h[(pedge[i] >> SRC_BITS) & 511], 1);
    __syncthreads();
    for (int off = 1; off < 512; off <<= 1) {
        int v0 = (t >= off) ? h[t - off] : 0;
        int v1 = (t + 256 >= off) ? h[t + 256 - off] : 0;
        __syncthreads();
        h[t] += v0;
        h[t + 256] += v1;
        __syncthreads();
    }
#pragma unroll
    for (int r = 0; r < 2; ++r) {
        int j = t + r * 256;
        int exc = j ? h[j - 1] : 0;
        cur[j] = exc;
        int n = (b << 9) + j;
        if (n < N) {
            seg[n] = bb0 + exc;
            norm_dst[n] = rsqrtf(fmaxf((float)(h[j] - exc), 1.0f));
        }
    }
    if (b == 0 && t == 0) seg[N] = E;
    __syncthreads();
    const int cnt = bb1 - bb0;
    for (int i = bb0 + t; i < bb1; i += 256) {
        int v = pedge[i];
        int j = (v >> SRC_BITS) & 511;
        int p = atomicAdd(&cur[j], 1);
        int s = v & ((1 << SRC_BITS) - 1);
        if (p < MAXB) stage[p] = s; else esrc[bb0 + p] = s;
    }
    __syncthreads();
    for (int i = t; i < cnt && i < MAXB; i += 256) esrc[bb0 + i] = stage[i];
}

// ---------------- S2: per-bucket src histogram -> norm_src ----------------
__global__ __launch_bounds__(256) void s2_kernel(const int* __restrict__ pedge, const int* __restrict__ scan,
                                                 float* __restrict__ norm_src, int N, int B1, int nbuk) {
    __shared__ int h[512];
    const int t = threadIdx.x;
    const int b = blockIdx.x;
    h[t] = 0; h[t + 256] = 0;
    __syncthreads();
    const int sb0 = scan[(nbuk + b) * B1];
    const int sb1 = scan[(nbuk + b + 1) * B1];
    for (int i = sb0 + t; i < sb1; i += 256) atomicAdd(&h[pedge[i] & 511], 1);
    __syncthreads();
#pragma unroll
    for (int r = 0; r < 2; ++r) {
        int j = t + r * 256;
        int n = (b << 9) + j;
        if (n < N) norm_src[n] = rsqrtf(fmaxf((float)h[j], 1.0f));
    }
}

// ---------------- X = (H @ W) * norm_row  (R4 version, known-good) ----------------
#define FMA4(s, wv, i) acc[i][0] += (s) * wv.x; acc[i][1] += (s) * wv.y; \
                       acc[i][2] += (s) * wv.z; acc[i][3] += (s) * wv.w;
template<int K>
__global__ __launch_bounds__(256) void gemm_norm(const float* __restrict__ H,
                                                 const float* __restrict__ W,
                                                 const float* __restrict__ norm,
                                                 float* __restrict__ X, int N) {
    constexpr int BK = 32;
    constexpr int NCH = K / BK;
    __shared__ __align__(16) float sH[64 * 36];   // [node][k], pad->stride 36
    __shared__ __align__(16) float sW[BK * 64];   // [k][col]
    const int tid = threadIdx.x;
    const int n0 = blockIdx.x * 64;
    const int tx = tid & 15;          // cols 4tx..4tx+3
    const int ty = tid >> 4;          // nodes 4ty..4ty+3

    const int hr = tid >> 3;          // 0..31 (plus +32 second half)
    const int hc = (tid & 7) * 4;     // float4 col within chunk
    const int wk = tid >> 4;          // 0..15 (plus +16)
    const int wc = (tid & 15) * 4;

    float4 hA, hB, wA, wB;
    const float4 zero4 = {0.0f, 0.0f, 0.0f, 0.0f};

    {
        int r0 = n0 + hr, r1 = n0 + hr + 32;
        hA = (r0 < N) ? *(const float4*)&H[(size_t)r0 * K + hc] : zero4;
        hB = (r1 < N) ? *(const float4*)&H[(size_t)r1 * K + hc] : zero4;
        wA = *(const float4*)&W[(size_t)wk * 64 + wc];
        wB = *(const float4*)&W[(size_t)(wk + 16) * 64 + wc];
    }

    float acc[4][4];
#pragma unroll
    for (int i = 0; i < 4; ++i)
#pragma unroll
        for (int m = 0; m < 4; ++m) acc[i][m] = 0.0f;

    for (int c = 0; c < NCH; ++c) {
        __syncthreads();
        *(float4*)&sH[hr * 36 + hc] = hA;
        *(float4*)&sH[(hr + 32) * 36 + hc] = hB;
        *(float4*)&sW[wk * 64 + wc] = wA;
        *(float4*)&sW[(wk + 16) * 64 + wc] = wB;
        __syncthreads();
        if (c + 1 < NCH) {
            int k0 = (c + 1) * BK;
            int r0 = n0 + hr, r1 = n0 + hr + 32;
            hA = (r0 < N) ? *(const float4*)&H[(size_t)r0 * K + k0 + hc] : zero4;
            hB = (r1 < N) ? *(const float4*)&H[(size_t)r1 * K + k0 + hc] : zero4;
            wA = *(const float4*)&W[(size_t)(k0 + wk) * 64 + wc];
            wB = *(const float4*)&W[(size_t)(k0 + wk + 16) * 64 + wc];
        }
#pragma unroll
        for (int kk = 0; kk < BK; kk += 4) {
            const float4 a0 = *(const float4*)&sH[(4 * ty + 0) * 36 + kk];
            const float4 a1 = *(const float4*)&sH[(4 * ty + 1) * 36 + kk];
            const float4 a2 = *(const float4*)&sH[(4 * ty + 2) * 36 + kk];
            const float4 a3 = *(const float4*)&sH[(4 * ty + 3) * 36 + kk];
            const float4 w0 = *(const float4*)&sW[(kk + 0) * 64 + 4 * tx];
            const float4 w1 = *(const float4*)&sW[(kk + 1) * 64 + 4 * tx];
            const float4 w2 = *(const float4*)&sW[(kk + 2) * 64 + 4 * tx];
            const float4 w3 = *(const float4*)&sW[(kk + 3) * 64 + 4 * tx];
            FMA4(a0.x, w0, 0) FMA4(a1.x, w0, 1) FMA4(a2.x, w0, 2) FMA4(a3.x, w0, 3)
            FMA4(a0.y, w1, 0) FMA4(a1.y, w1, 1) FMA4(a2.y, w1, 2) FMA4(a3.y, w1, 3)
            FMA4(a0.z, w2, 0) FMA4(a1.z, w2, 1) FMA4(a2.z, w2, 2) FMA4(a3.z, w2, 3)
            FMA4(a0.w, w3, 0) FMA4(a1.w, w3, 1) FMA4(a2.w, w3, 2) FMA4(a3.w, w3, 3)
        }
    }

#pragma unroll
    for (int i = 0; i < 4; ++i) {
        int n = n0 + 4 * ty + i;
        if (n < N) {
            float s = norm[n];
            float4 o;
            o.x = acc[i][0] * s; o.y = acc[i][1] * s; o.z = acc[i][2] * s; o.w = acc[i][3] * s;
            *(float4*)&X[(size_t)n * 64 + 4 * tx] = o;
        }
    }
}

// ---------------- segment sum over CSR, half the features per pass ----------------
// lanes 0-31: edge e, lanes 32-63: edge e+1; feature = (lane&31)+fofs.
// Working set per pass = 12.8 MB (vs 4 MB L2/XCD) -> better hit rate.
template<bool ELU>
__global__ __launch_bounds__(256) void segsum_half_kernel(const float* __restrict__ X,
                                                          const int* __restrict__ esrc,
                                                          const int* __restrict__ seg,
                                                          const float* __restrict__ norm_dst,
                                                          const float* __restrict__ bias,
                                                          float* __restrict__ out, int N, int fofs) {
    const int node = blockIdx.x * 4 + (threadIdx.x >> 6);
    const int lane = threadIdx.x & 63;
    if (node >= N) return;
    const int eh = lane >> 5;              // which edge of the pair
    const int f = (lane & 31) + fofs;
    const int s0 = seg[node];
    const int s1 = seg[node + 1];
    float acc = 0.0f;
    int e = s0;
    for (; e + 8 <= s1; e += 8) {          // 4 pairs = 8 edges, 4 independent loads
        int a0 = esrc[e + 0 + eh];
        int a1 = esrc[e + 2 + eh];
        int a2 = esrc[e + 4 + eh];
        int a3 = esrc[e + 6 + eh];
        float v0 = X[(size_t)a0 * 64 + f];
        float v1 = X[(size_t)a1 * 64 + f];
        float v2 = X[(size_t)a2 * 64 + f];
        float v3 = X[(size_t)a3 * 64 + f];
        acc += v0; acc += v1; acc += v2; acc += v3;
    }
    for (; e + 2 <= s1; e += 2) acc += X[(size_t)esrc[e + eh] * 64 + f];
    if (e < s1 && eh == 0) acc += X[(size_t)esrc[e] * 64 + f];
    acc += __shfl(acc, lane ^ 32);         // merge the two edge-halves
    float r = acc * norm_dst[node] + bias[f];
    if (ELU) r = (r > 0.0f) ? r : expm1f(r);
    if (eh == 0) out[(size_t)node * 64 + f] = r;
}

extern "C" void kernel_launch(void* const* d_in, const int* in_sizes, int n_in,
                              void* d_out, int out_size, void* d_ws, size_t ws_size,
                              hipStream_t stream) {
    const float* h   = (const float*)d_in[0];
    const int*   src = (const int*)d_in[1];
    const int*   dst = (const int*)d_in[2];
    const float* W1  = (const float*)d_in[3];
    const float* b1  = (const float*)d_in[4];
    const float* W2  = (const float*)d_in[5];
    const float* b2  = (const float*)d_in[6];
    float* out = (float*)d_out;

    const int N = in_sizes[0] / 128;       // 100000
    const int E = in_sizes[1];             // 1600000
    const int nbuk = (N + 511) >> 9;       // 196
    const int B1 = (E + CH - 1) / CH;      // 391
    const int M = 2 * nbuk * B1;

    int* iw = (int*)d_ws;
    int* mat   = iw;
    int* scanb = mat + M;
    int* bsums = scanb + M + 4;
    int* pedge = bsums + 256;              // 2E
    int* esrc  = pedge + 2 * (size_t)E;    // E
    int* seg   = esrc + (size_t)E;         // N+1 (+pad)
    float* fw       = (float*)(seg + (size_t)N + 4);
    float* norm_src = fw;
    float* norm_dst = fw + (size_t)N;
    float* X        = fw + 2 * (size_t)N;
    float* H1       = X + 64 * (size_t)N;

    // ---- CSR build ----
    p1a_kernel<<<B1, 256, 0, stream>>>(src, dst, mat, E, B1, nbuk);
    const int G = (M + 1023) / 1024;
    scan1_kernel<<<G, 256, 0, stream>>>(mat, scanb, bsums, M);
    scan2_kernel<<<1, 256, 0, stream>>>(bsums, scanb, M, G);
    scan3_kernel<<<G, 256, 0, stream>>>(scanb, bsums, M);
    p1c_kernel<<<B1, 256, 0, stream>>>(src, dst, scanb, pedge, E, B1, nbuk);
    p2_kernel<<<nbuk, 256, 0, stream>>>(pedge, scanb, esrc, seg, norm_dst, N, E, B1);
    s2_kernel<<<nbuk, 256, 0, stream>>>(pedge, scanb, norm_src, N, B1, nbuk);

    const int segGrid = (N + 3) / 4;

    // ---- layer 1 ----
    gemm_norm<128><<<(N + 63) / 64, 256, 0, stream>>>(h, W1, norm_src, X, N);
    segsum_half_kernel<true><<<segGrid, 256, 0, stream>>>(X, esrc, seg, norm_dst, b1, H1, N, 0);
    segsum_half_kernel<true><<<segGrid, 256, 0, stream>>>(X, esrc, seg, norm_dst, b1, H1, N, 32);

    // ---- layer 2 ----
    gemm_norm<64><<<(N + 63) / 64, 256, 0, stream>>>(H1, W2, norm_src, X, N);
    segsum_half_kernel<false><<<segGrid, 256, 0, stream>>>(X, esrc, seg, norm_dst, b2, out, N, 0);
    segsum_half_kernel<false><<<segGrid, 256, 0, stream>>>(X, esrc, seg, norm_dst, b2, out, N, 32);
}

// Round 7
// 357.899 us; speedup vs baseline: 1.2747x; 1.2747x over previous
//
#include <hip/hip_runtime.h>
#include <math.h>

#define CH 4096        // edges per partition block
#define NBUK_MAX 256   // max buckets (N <= 131072)
#define MAXB 12288     // max edges per bucket staged in LDS (48 KB)
#define SRC_BITS 17    // N < 131072 fits in 17 bits

// bf16 <-> f32 helpers (RNE pack; exact unpack)
__device__ __forceinline__ unsigned short f2bf(float f) {
    union { float f; unsigned int u; } v; v.f = f;
    unsigned int r = (v.u + 0x7FFFu + ((v.u >> 16) & 1u)) >> 16;
    return (unsigned short)r;
}
__device__ __forceinline__ float bf2f(unsigned short u) {
    union { unsigned int u; float f; } v; v.u = ((unsigned int)u) << 16;
    return v.f;
}

// ---------------- P1a: per-block bucket histograms ----------------
__global__ __launch_bounds__(256) void p1a_kernel(const int* __restrict__ src, const int* __restrict__ dst,
                                                  int* __restrict__ mat, int E, int B1, int nbuk) {
    __shared__ int hd[NBUK_MAX], hs[NBUK_MAX];
    const int t = threadIdx.x;
    if (t < nbuk) { hd[t] = 0; hs[t] = 0; }
    __syncthreads();
    const int base = blockIdx.x * CH;
    const int cnt = min(CH, E - base);
    for (int k = t; k < cnt; k += 256) {
        int d = dst[base + k];
        int s = src[base + k];
        atomicAdd(&hd[d >> 9], 1);
        atomicAdd(&hs[s >> 9], 1);
    }
    __syncthreads();
    if (t < nbuk) {
        mat[t * B1 + blockIdx.x] = hd[t];
        mat[(nbuk + t) * B1 + blockIdx.x] = hs[t];
    }
}

// ---------------- 3-phase exclusive scan ----------------
__global__ __launch_bounds__(256) void scan1_kernel(const int* __restrict__ cnt,
                                                    int* __restrict__ seg,
                                                    int* __restrict__ bsums, int N) {
    __shared__ int tsum[256];
    const int t = threadIdx.x;
    const int base = blockIdx.x * 1024 + t * 4;
    int v0 = (base + 0 < N) ? cnt[base + 0] : 0;
    int v1 = (base + 1 < N) ? cnt[base + 1] : 0;
    int v2 = (base + 2 < N) ? cnt[base + 2] : 0;
    int v3 = (base + 3 < N) ? cnt[base + 3] : 0;
    tsum[t] = v0 + v1 + v2 + v3;
    __syncthreads();
    for (int off = 1; off < 256; off <<= 1) {
        int x = (t >= off) ? tsum[t - off] : 0;
        __syncthreads();
        if (t >= off) tsum[t] += x;
        __syncthreads();
    }
    int run = (t > 0) ? tsum[t - 1] : 0;
    if (base + 0 < N) seg[base + 0] = run; run += v0;
    if (base + 1 < N) seg[base + 1] = run; run += v1;
    if (base + 2 < N) seg[base + 2] = run; run += v2;
    if (base + 3 < N) seg[base + 3] = run;
    if (t == 255) bsums[blockIdx.x] = tsum[255];
}

__global__ void scan2_kernel(int* __restrict__ bsums, int* __restrict__ seg, int N, int G) {
    __shared__ int s[256];
    int t = threadIdx.x;
    if (t < G) s[t] = bsums[t];
    __syncthreads();
    if (t == 0) {
        int run = 0;
        for (int i = 0; i < G; ++i) { int v = s[i]; s[i] = run; run += v; }
        seg[N] = run;
    }
    __syncthreads();
    if (t < G) bsums[t] = s[t];
}

__global__ __launch_bounds__(256) void scan3_kernel(int* __restrict__ seg,
                                                    const int* __restrict__ bsums, int N) {
    int add = bsums[blockIdx.x];
    int base = blockIdx.x * 1024 + threadIdx.x * 4;
#pragma unroll
    for (int i = 0; i < 4; ++i) {
        int idx = base + i;
        if (idx < N) seg[idx] += add;
    }
}

// ---------------- P1c: LDS-staged partition scatter ----------------
__global__ __launch_bounds__(256) void p1c_kernel(const int* __restrict__ src, const int* __restrict__ dst,
                                                  const int* __restrict__ scan,
                                                  int* __restrict__ pedge,
                                                  int E, int B1, int nbuk) {
    __shared__ int hd[NBUK_MAX], hs[NBUK_MAX];
    __shared__ int curD[NBUK_MAX], curS[NBUK_MAX];
    __shared__ int baseD[NBUK_MAX], baseS[NBUK_MAX];
    __shared__ int stD[CH];
    __shared__ int stS[CH];
    const int t = threadIdx.x;
    if (t < nbuk) { hd[t] = 0; hs[t] = 0; }
    __syncthreads();
    const int base = blockIdx.x * CH;
    const int cnt = min(CH, E - base);
    int dl[CH / 256], sl[CH / 256];
#pragma unroll
    for (int k = 0; k < CH / 256; ++k) {
        int i = t + k * 256;
        if (i < cnt) {
            dl[k] = dst[base + i];
            sl[k] = src[base + i];
            atomicAdd(&hd[dl[k] >> 9], 1);
            atomicAdd(&hs[sl[k] >> 9], 1);
        }
    }
    __syncthreads();
    for (int off = 1; off < nbuk; off <<= 1) {
        int v0 = (t >= off && t < nbuk) ? hd[t - off] : 0;
        int w0 = (t >= off && t < nbuk) ? hs[t - off] : 0;
        __syncthreads();
        if (t < nbuk) { hd[t] += v0; hs[t] += w0; }
        __syncthreads();
    }
    if (t < nbuk) {
        int excD = t ? hd[t - 1] : 0;
        int excS = t ? hs[t - 1] : 0;
        curD[t] = excD;
        curS[t] = excS;
        baseD[t] = scan[t * B1 + blockIdx.x] - excD;
        baseS[t] = scan[(nbuk + t) * B1 + blockIdx.x] - excS;
    }
    __syncthreads();
#pragma unroll
    for (int k = 0; k < CH / 256; ++k) {
        int i = t + k * 256;
        if (i < cnt) {
            int j = dl[k] >> 9;
            int p = atomicAdd(&curD[j], 1);
            stD[p] = ((dl[k] & 511) << SRC_BITS) | sl[k];
            int jq = sl[k] >> 9;
            int q = atomicAdd(&curS[jq], 1);
            stS[q] = sl[k];
        }
    }
    __syncthreads();
    for (int i = t; i < cnt; i += 256) {
        int lo = 0, hi = nbuk - 1;
        while (lo < hi) { int mid = (lo + hi) >> 1; if (hd[mid] > i) hi = mid; else lo = mid + 1; }
        pedge[baseD[lo] + i] = stD[i];
        int lo2 = 0, hi2 = nbuk - 1;
        while (lo2 < hi2) { int mid = (lo2 + hi2) >> 1; if (hs[mid] > i) hi2 = mid; else lo2 = mid + 1; }
        pedge[baseS[lo2] + i] = stS[i];
    }
}

// ---------------- P2: per-bucket local sort -> esrc, seg, norm_dst ----------------
__global__ __launch_bounds__(256) void p2_kernel(const int* __restrict__ pedge,
                                                 const int* __restrict__ scan,
                                                 int* __restrict__ esrc, int* __restrict__ seg,
                                                 float* __restrict__ norm_dst,
                                                 int N, int E, int B1) {
    __shared__ int h[512];
    __shared__ int cur[512];
    __shared__ int stage[MAXB];
    const int t = threadIdx.x;
    const int b = blockIdx.x;
    h[t] = 0; h[t + 256] = 0;
    __syncthreads();
    const int bb0 = scan[b * B1];
    const int bb1 = scan[(b + 1) * B1];
    for (int i = bb0 + t; i < bb1; i += 256) atomicAdd(&h[(pedge[i] >> SRC_BITS) & 511], 1);
    __syncthreads();
    for (int off = 1; off < 512; off <<= 1) {
        int v0 = (t >= off) ? h[t - off] : 0;
        int v1 = (t + 256 >= off) ? h[t + 256 - off] : 0;
        __syncthreads();
        h[t] += v0;
        h[t + 256] += v1;
        __syncthreads();
    }
#pragma unroll
    for (int r = 0; r < 2; ++r) {
        int j = t + r * 256;
        int exc = j ? h[j - 1] : 0;
        cur[j] = exc;
        int n = (b << 9) + j;
        if (n < N) {
            seg[n] = bb0 + exc;
            norm_dst[n] = rsqrtf(fmaxf((float)(h[j] - exc), 1.0f));
        }
    }
    if (b == 0 && t == 0) seg[N] = E;
    __syncthreads();
    const int cnt = bb1 - bb0;
    for (int i = bb0 + t; i < bb1; i += 256) {
        int v = pedge[i];
        int j = (v >> SRC_BITS) & 511;
        int p = atomicAdd(&cur[j], 1);
        int s = v & ((1 << SRC_BITS) - 1);
        if (p < MAXB) stage[p] = s; else esrc[bb0 + p] = s;
    }
    __syncthreads();
    for (int i = t; i < cnt && i < MAXB; i += 256) esrc[bb0 + i] = stage[i];
}

// ---------------- S2: per-bucket src histogram -> norm_src ----------------
__global__ __launch_bounds__(256) void s2_kernel(const int* __restrict__ pedge, const int* __restrict__ scan,
                                                 float* __restrict__ norm_src, int N, int B1, int nbuk) {
    __shared__ int h[512];
    const int t = threadIdx.x;
    const int b = blockIdx.x;
    h[t] = 0; h[t + 256] = 0;
    __syncthreads();
    const int sb0 = scan[(nbuk + b) * B1];
    const int sb1 = scan[(nbuk + b + 1) * B1];
    for (int i = sb0 + t; i < sb1; i += 256) atomicAdd(&h[pedge[i] & 511], 1);
    __syncthreads();
#pragma unroll
    for (int r = 0; r < 2; ++r) {
        int j = t + r * 256;
        int n = (b << 9) + j;
        if (n < N) norm_src[n] = rsqrtf(fmaxf((float)h[j], 1.0f));
    }
}

// ---------------- X(bf16) = (H @ W) * norm_row  (R4 structure, bf16 epilogue) ----------------
#define FMA4(s, wv, i) acc[i][0] += (s) * wv.x; acc[i][1] += (s) * wv.y; \
                       acc[i][2] += (s) * wv.z; acc[i][3] += (s) * wv.w;
template<int K>
__global__ __launch_bounds__(256) void gemm_norm(const float* __restrict__ H,
                                                 const float* __restrict__ W,
                                                 const float* __restrict__ norm,
                                                 unsigned short* __restrict__ X, int N) {
    constexpr int BK = 32;
    constexpr int NCH = K / BK;
    __shared__ __align__(16) float sH[64 * 36];   // [node][k], pad->stride 36
    __shared__ __align__(16) float sW[BK * 64];   // [k][col]
    const int tid = threadIdx.x;
    const int n0 = blockIdx.x * 64;
    const int tx = tid & 15;          // cols 4tx..4tx+3
    const int ty = tid >> 4;          // nodes 4ty..4ty+3

    const int hr = tid >> 3;
    const int hc = (tid & 7) * 4;
    const int wk = tid >> 4;
    const int wc = (tid & 15) * 4;

    float4 hA, hB, wA, wB;
    const float4 zero4 = {0.0f, 0.0f, 0.0f, 0.0f};

    {
        int r0 = n0 + hr, r1 = n0 + hr + 32;
        hA = (r0 < N) ? *(const float4*)&H[(size_t)r0 * K + hc] : zero4;
        hB = (r1 < N) ? *(const float4*)&H[(size_t)r1 * K + hc] : zero4;
        wA = *(const float4*)&W[(size_t)wk * 64 + wc];
        wB = *(const float4*)&W[(size_t)(wk + 16) * 64 + wc];
    }

    float acc[4][4];
#pragma unroll
    for (int i = 0; i < 4; ++i)
#pragma unroll
        for (int m = 0; m < 4; ++m) acc[i][m] = 0.0f;

    for (int c = 0; c < NCH; ++c) {
        __syncthreads();
        *(float4*)&sH[hr * 36 + hc] = hA;
        *(float4*)&sH[(hr + 32) * 36 + hc] = hB;
        *(float4*)&sW[wk * 64 + wc] = wA;
        *(float4*)&sW[(wk + 16) * 64 + wc] = wB;
        __syncthreads();
        if (c + 1 < NCH) {
            int k0 = (c + 1) * BK;
            int r0 = n0 + hr, r1 = n0 + hr + 32;
            hA = (r0 < N) ? *(const float4*)&H[(size_t)r0 * K + k0 + hc] : zero4;
            hB = (r1 < N) ? *(const float4*)&H[(size_t)r1 * K + k0 + hc] : zero4;
            wA = *(const float4*)&W[(size_t)(k0 + wk) * 64 + wc];
            wB = *(const float4*)&W[(size_t)(k0 + wk + 16) * 64 + wc];
        }
#pragma unroll
        for (int kk = 0; kk < BK; kk += 4) {
            const float4 a0 = *(const float4*)&sH[(4 * ty + 0) * 36 + kk];
            const float4 a1 = *(const float4*)&sH[(4 * ty + 1) * 36 + kk];
            const float4 a2 = *(const float4*)&sH[(4 * ty + 2) * 36 + kk];
            const float4 a3 = *(const float4*)&sH[(4 * ty + 3) * 36 + kk];
            const float4 w0 = *(const float4*)&sW[(kk + 0) * 64 + 4 * tx];
            const float4 w1 = *(const float4*)&sW[(kk + 1) * 64 + 4 * tx];
            const float4 w2 = *(const float4*)&sW[(kk + 2) * 64 + 4 * tx];
            const float4 w3 = *(const float4*)&sW[(kk + 3) * 64 + 4 * tx];
            FMA4(a0.x, w0, 0) FMA4(a1.x, w0, 1) FMA4(a2.x, w0, 2) FMA4(a3.x, w0, 3)
            FMA4(a0.y, w1, 0) FMA4(a1.y, w1, 1) FMA4(a2.y, w1, 2) FMA4(a3.y, w1, 3)
            FMA4(a0.z, w2, 0) FMA4(a1.z, w2, 1) FMA4(a2.z, w2, 2) FMA4(a3.z, w2, 3)
            FMA4(a0.w, w3, 0) FMA4(a1.w, w3, 1) FMA4(a2.w, w3, 2) FMA4(a3.w, w3, 3)
        }
    }

#pragma unroll
    for (int i = 0; i < 4; ++i) {
        int n = n0 + 4 * ty + i;
        if (n < N) {
            float s = norm[n];
            ushort4 o;
            o.x = f2bf(acc[i][0] * s);
            o.y = f2bf(acc[i][1] * s);
            o.z = f2bf(acc[i][2] * s);
            o.w = f2bf(acc[i][3] * s);
            *(ushort4*)&X[(size_t)n * 64 + 4 * tx] = o;
        }
    }
}

// ---------------- segment sum over CSR (bf16 X rows) + fused epilogue ----------------
// one wave per node, lane = feature; fp32 accumulation.
template<bool ELU>
__global__ __launch_bounds__(256) void segsum_kernel(const unsigned short* __restrict__ X,
                                                     const int* __restrict__ esrc,
                                                     const int* __restrict__ seg,
                                                     const float* __restrict__ norm_dst,
                                                     const float* __restrict__ b,
                                                     float* __restrict__ out, int N) {
    const int node = blockIdx.x * 4 + (threadIdx.x >> 6);
    const int lane = threadIdx.x & 63;
    if (node >= N) return;
    const int s0 = seg[node];
    const int s1 = seg[node + 1];
    float acc = 0.0f;
    int e = s0;
    for (; e + 8 <= s1; e += 8) {
        int a0 = esrc[e + 0]; int a1 = esrc[e + 1];
        int a2 = esrc[e + 2]; int a3 = esrc[e + 3];
        int a4 = esrc[e + 4]; int a5 = esrc[e + 5];
        int a6 = esrc[e + 6]; int a7 = esrc[e + 7];
        unsigned short u0 = X[(size_t)a0 * 64 + lane];
        unsigned short u1 = X[(size_t)a1 * 64 + lane];
        unsigned short u2 = X[(size_t)a2 * 64 + lane];
        unsigned short u3 = X[(size_t)a3 * 64 + lane];
        unsigned short u4 = X[(size_t)a4 * 64 + lane];
        unsigned short u5 = X[(size_t)a5 * 64 + lane];
        unsigned short u6 = X[(size_t)a6 * 64 + lane];
        unsigned short u7 = X[(size_t)a7 * 64 + lane];
        acc += bf2f(u0); acc += bf2f(u1); acc += bf2f(u2); acc += bf2f(u3);
        acc += bf2f(u4); acc += bf2f(u5); acc += bf2f(u6); acc += bf2f(u7);
    }
    for (; e < s1; ++e) acc += bf2f(X[(size_t)esrc[e] * 64 + lane]);
    float r = acc * norm_dst[node] + b[lane];
    if (ELU) r = (r > 0.0f) ? r : expm1f(r);
    out[(size_t)node * 64 + lane] = r;
}

extern "C" void kernel_launch(void* const* d_in, const int* in_sizes, int n_in,
                              void* d_out, int out_size, void* d_ws, size_t ws_size,
                              hipStream_t stream) {
    const float* h   = (const float*)d_in[0];
    const int*   src = (const int*)d_in[1];
    const int*   dst = (const int*)d_in[2];
    const float* W1  = (const float*)d_in[3];
    const float* b1  = (const float*)d_in[4];
    const float* W2  = (const float*)d_in[5];
    const float* b2  = (const float*)d_in[6];
    float* out = (float*)d_out;

    const int N = in_sizes[0] / 128;       // 100000
    const int E = in_sizes[1];             // 1600000
    const int nbuk = (N + 511) >> 9;       // 196
    const int B1 = (E + CH - 1) / CH;      // 391
    const int M = 2 * nbuk * B1;

    int* iw = (int*)d_ws;
    int* mat   = iw;
    int* scanb = mat + M;
    int* bsums = scanb + M + 4;
    int* pedge = bsums + 256;              // 2E
    int* esrc  = pedge + 2 * (size_t)E;    // E
    int* seg   = esrc + (size_t)E;         // N+1 (+pad)
    float* fw       = (float*)(seg + (size_t)N + 4);
    float* norm_src = fw;
    float* norm_dst = fw + (size_t)N;
    float* H1       = fw + 2 * (size_t)N;              // 64N floats
    unsigned short* Xb = (unsigned short*)(H1 + 64 * (size_t)N);  // 64N bf16

    // ---- CSR build ----
    p1a_kernel<<<B1, 256, 0, stream>>>(src, dst, mat, E, B1, nbuk);
    const int G = (M + 1023) / 1024;
    scan1_kernel<<<G, 256, 0, stream>>>(mat, scanb, bsums, M);
    scan2_kernel<<<1, 256, 0, stream>>>(bsums, scanb, M, G);
    scan3_kernel<<<G, 256, 0, stream>>>(scanb, bsums, M);
    p1c_kernel<<<B1, 256, 0, stream>>>(src, dst, scanb, pedge, E, B1, nbuk);
    p2_kernel<<<nbuk, 256, 0, stream>>>(pedge, scanb, esrc, seg, norm_dst, N, E, B1);
    s2_kernel<<<nbuk, 256, 0, stream>>>(pedge, scanb, norm_src, N, B1, nbuk);

    const int segGrid = (N + 3) / 4;

    // ---- layer 1 ----
    gemm_norm<128><<<(N + 63) / 64, 256, 0, stream>>>(h, W1, norm_src, Xb, N);
    segsum_kernel<true><<<segGrid, 256, 0, stream>>>(Xb, esrc, seg, norm_dst, b1, H1, N);

    // ---- layer 2 ----
    gemm_norm<64><<<(N + 63) / 64, 256, 0, stream>>>(H1, W2, norm_src, Xb, N);
    segsum_kernel<false><<<segGrid, 256, 0, stream>>>(Xb, esrc, seg, norm_dst, b2, out, N);
}

// Round 8
// 331.892 us; speedup vs baseline: 1.3746x; 1.0784x over previous
//
#include <hip/hip_runtime.h>
#include <math.h>

#define CH 4096        // edges per partition block
#define NBUK_MAX 256   // max buckets (N <= 131072)
#define MAXB 12288     // max edges per bucket staged in LDS (48 KB)
#define SRC_BITS 17    // N < 131072 fits in 17 bits

// bf16 <-> f32 helpers (RNE pack; exact unpack)
__device__ __forceinline__ unsigned short f2bf(float f) {
    union { float f; unsigned int u; } v; v.f = f;
    unsigned int r = (v.u + 0x7FFFu + ((v.u >> 16) & 1u)) >> 16;
    return (unsigned short)r;
}
__device__ __forceinline__ float bf2f(unsigned short u) {
    union { unsigned int u; float f; } v; v.u = ((unsigned int)u) << 16;
    return v.f;
}
// unpack packed pair (low ushort = even feature, high = odd)
__device__ __forceinline__ float bflo(unsigned int u) {
    union { unsigned int u; float f; } v; v.u = u << 16;
    return v.f;
}
__device__ __forceinline__ float bfhi(unsigned int u) {
    union { unsigned int u; float f; } v; v.u = u & 0xFFFF0000u;
    return v.f;
}

// ---------------- P1a: per-block bucket histograms ----------------
__global__ __launch_bounds__(256) void p1a_kernel(const int* __restrict__ src, const int* __restrict__ dst,
                                                  int* __restrict__ mat, int E, int B1, int nbuk) {
    __shared__ int hd[NBUK_MAX], hs[NBUK_MAX];
    const int t = threadIdx.x;
    if (t < nbuk) { hd[t] = 0; hs[t] = 0; }
    __syncthreads();
    const int base = blockIdx.x * CH;
    const int cnt = min(CH, E - base);
    for (int k = t; k < cnt; k += 256) {
        int d = dst[base + k];
        int s = src[base + k];
        atomicAdd(&hd[d >> 9], 1);
        atomicAdd(&hs[s >> 9], 1);
    }
    __syncthreads();
    if (t < nbuk) {
        mat[t * B1 + blockIdx.x] = hd[t];
        mat[(nbuk + t) * B1 + blockIdx.x] = hs[t];
    }
}

// ---------------- 3-phase exclusive scan ----------------
__global__ __launch_bounds__(256) void scan1_kernel(const int* __restrict__ cnt,
                                                    int* __restrict__ seg,
                                                    int* __restrict__ bsums, int N) {
    __shared__ int tsum[256];
    const int t = threadIdx.x;
    const int base = blockIdx.x * 1024 + t * 4;
    int v0 = (base + 0 < N) ? cnt[base + 0] : 0;
    int v1 = (base + 1 < N) ? cnt[base + 1] : 0;
    int v2 = (base + 2 < N) ? cnt[base + 2] : 0;
    int v3 = (base + 3 < N) ? cnt[base + 3] : 0;
    tsum[t] = v0 + v1 + v2 + v3;
    __syncthreads();
    for (int off = 1; off < 256; off <<= 1) {
        int x = (t >= off) ? tsum[t - off] : 0;
        __syncthreads();
        if (t >= off) tsum[t] += x;
        __syncthreads();
    }
    int run = (t > 0) ? tsum[t - 1] : 0;
    if (base + 0 < N) seg[base + 0] = run; run += v0;
    if (base + 1 < N) seg[base + 1] = run; run += v1;
    if (base + 2 < N) seg[base + 2] = run; run += v2;
    if (base + 3 < N) seg[base + 3] = run;
    if (t == 255) bsums[blockIdx.x] = tsum[255];
}

__global__ void scan2_kernel(int* __restrict__ bsums, int* __restrict__ seg, int N, int G) {
    __shared__ int s[256];
    int t = threadIdx.x;
    if (t < G) s[t] = bsums[t];
    __syncthreads();
    if (t == 0) {
        int run = 0;
        for (int i = 0; i < G; ++i) { int v = s[i]; s[i] = run; run += v; }
        seg[N] = run;
    }
    __syncthreads();
    if (t < G) bsums[t] = s[t];
}

__global__ __launch_bounds__(256) void scan3_kernel(int* __restrict__ seg,
                                                    const int* __restrict__ bsums, int N) {
    int add = bsums[blockIdx.x];
    int base = blockIdx.x * 1024 + threadIdx.x * 4;
#pragma unroll
    for (int i = 0; i < 4; ++i) {
        int idx = base + i;
        if (idx < N) seg[idx] += add;
    }
}

// ---------------- P1c: LDS-staged partition scatter ----------------
__global__ __launch_bounds__(256) void p1c_kernel(const int* __restrict__ src, const int* __restrict__ dst,
                                                  const int* __restrict__ scan,
                                                  int* __restrict__ pedge,
                                                  int E, int B1, int nbuk) {
    __shared__ int hd[NBUK_MAX], hs[NBUK_MAX];
    __shared__ int curD[NBUK_MAX], curS[NBUK_MAX];
    __shared__ int baseD[NBUK_MAX], baseS[NBUK_MAX];
    __shared__ int stD[CH];
    __shared__ int stS[CH];
    const int t = threadIdx.x;
    if (t < nbuk) { hd[t] = 0; hs[t] = 0; }
    __syncthreads();
    const int base = blockIdx.x * CH;
    const int cnt = min(CH, E - base);
    int dl[CH / 256], sl[CH / 256];
#pragma unroll
    for (int k = 0; k < CH / 256; ++k) {
        int i = t + k * 256;
        if (i < cnt) {
            dl[k] = dst[base + i];
            sl[k] = src[base + i];
            atomicAdd(&hd[dl[k] >> 9], 1);
            atomicAdd(&hs[sl[k] >> 9], 1);
        }
    }
    __syncthreads();
    for (int off = 1; off < nbuk; off <<= 1) {
        int v0 = (t >= off && t < nbuk) ? hd[t - off] : 0;
        int w0 = (t >= off && t < nbuk) ? hs[t - off] : 0;
        __syncthreads();
        if (t < nbuk) { hd[t] += v0; hs[t] += w0; }
        __syncthreads();
    }
    if (t < nbuk) {
        int excD = t ? hd[t - 1] : 0;
        int excS = t ? hs[t - 1] : 0;
        curD[t] = excD;
        curS[t] = excS;
        baseD[t] = scan[t * B1 + blockIdx.x] - excD;
        baseS[t] = scan[(nbuk + t) * B1 + blockIdx.x] - excS;
    }
    __syncthreads();
#pragma unroll
    for (int k = 0; k < CH / 256; ++k) {
        int i = t + k * 256;
        if (i < cnt) {
            int j = dl[k] >> 9;
            int p = atomicAdd(&curD[j], 1);
            stD[p] = ((dl[k] & 511) << SRC_BITS) | sl[k];
            int jq = sl[k] >> 9;
            int q = atomicAdd(&curS[jq], 1);
            stS[q] = sl[k];
        }
    }
    __syncthreads();
    for (int i = t; i < cnt; i += 256) {
        int lo = 0, hi = nbuk - 1;
        while (lo < hi) { int mid = (lo + hi) >> 1; if (hd[mid] > i) hi = mid; else lo = mid + 1; }
        pedge[baseD[lo] + i] = stD[i];
        int lo2 = 0, hi2 = nbuk - 1;
        while (lo2 < hi2) { int mid = (lo2 + hi2) >> 1; if (hs[mid] > i) hi2 = mid; else lo2 = mid + 1; }
        pedge[baseS[lo2] + i] = stS[i];
    }
}

// ---------------- P2: per-bucket local sort -> esrc, seg, norm_dst ----------------
__global__ __launch_bounds__(256) void p2_kernel(const int* __restrict__ pedge,
                                                 const int* __restrict__ scan,
                                                 int* __restrict__ esrc, int* __restrict__ seg,
                                                 float* __restrict__ norm_dst,
                                                 int N, int E, int B1) {
    __shared__ int h[512];
    __shared__ int cur[512];
    __shared__ int stage[MAXB];
    const int t = threadIdx.x;
    const int b = blockIdx.x;
    h[t] = 0; h[t + 256] = 0;
    __syncthreads();
    const int bb0 = scan[b * B1];
    const int bb1 = scan[(b + 1) * B1];
    for (int i = bb0 + t; i < bb1; i += 256) atomicAdd(&h[(pedge[i] >> SRC_BITS) & 511], 1);
    __syncthreads();
    for (int off = 1; off < 512; off <<= 1) {
        int v0 = (t >= off) ? h[t - off] : 0;
        int v1 = (t + 256 >= off) ? h[t + 256 - off] : 0;
        __syncthreads();
        h[t] += v0;
        h[t + 256] += v1;
        __syncthreads();
    }
#pragma unroll
    for (int r = 0; r < 2; ++r) {
        int j = t + r * 256;
        int exc = j ? h[j - 1] : 0;
        cur[j] = exc;
        int n = (b << 9) + j;
        if (n < N) {
            seg[n] = bb0 + exc;
            norm_dst[n] = rsqrtf(fmaxf((float)(h[j] - exc), 1.0f));
        }
    }
    if (b == 0 && t == 0) seg[N] = E;
    __syncthreads();
    const int cnt = bb1 - bb0;
    for (int i = bb0 + t; i < bb1; i += 256) {
        int v = pedge[i];
        int j = (v >> SRC_BITS) & 511;
        int p = atomicAdd(&cur[j], 1);
        int s = v & ((1 << SRC_BITS) - 1);
        if (p < MAXB) stage[p] = s; else esrc[bb0 + p] = s;
    }
    __syncthreads();
    for (int i = t; i < cnt && i < MAXB; i += 256) esrc[bb0 + i] = stage[i];
}

// ---------------- S2: per-bucket src histogram -> norm_src ----------------
__global__ __launch_bounds__(256) void s2_kernel(const int* __restrict__ pedge, const int* __restrict__ scan,
                                                 float* __restrict__ norm_src, int N, int B1, int nbuk) {
    __shared__ int h[512];
    const int t = threadIdx.x;
    const int b = blockIdx.x;
    h[t] = 0; h[t + 256] = 0;
    __syncthreads();
    const int sb0 = scan[(nbuk + b) * B1];
    const int sb1 = scan[(nbuk + b + 1) * B1];
    for (int i = sb0 + t; i < sb1; i += 256) atomicAdd(&h[pedge[i] & 511], 1);
    __syncthreads();
#pragma unroll
    for (int r = 0; r < 2; ++r) {
        int j = t + r * 256;
        int n = (b << 9) + j;
        if (n < N) norm_src[n] = rsqrtf(fmaxf((float)h[j], 1.0f));
    }
}

// ---------------- X(bf16) = (H @ W) * norm_row  (R4 structure, bf16 epilogue) ----------------
#define FMA4(s, wv, i) acc[i][0] += (s) * wv.x; acc[i][1] += (s) * wv.y; \
                       acc[i][2] += (s) * wv.z; acc[i][3] += (s) * wv.w;
template<int K>
__global__ __launch_bounds__(256) void gemm_norm(const float* __restrict__ H,
                                                 const float* __restrict__ W,
                                                 const float* __restrict__ norm,
                                                 unsigned short* __restrict__ X, int N) {
    constexpr int BK = 32;
    constexpr int NCH = K / BK;
    __shared__ __align__(16) float sH[64 * 36];   // [node][k], pad->stride 36
    __shared__ __align__(16) float sW[BK * 64];   // [k][col]
    const int tid = threadIdx.x;
    const int n0 = blockIdx.x * 64;
    const int tx = tid & 15;          // cols 4tx..4tx+3
    const int ty = tid >> 4;          // nodes 4ty..4ty+3

    const int hr = tid >> 3;
    const int hc = (tid & 7) * 4;
    const int wk = tid >> 4;
    const int wc = (tid & 15) * 4;

    float4 hA, hB, wA, wB;
    const float4 zero4 = {0.0f, 0.0f, 0.0f, 0.0f};

    {
        int r0 = n0 + hr, r1 = n0 + hr + 32;
        hA = (r0 < N) ? *(const float4*)&H[(size_t)r0 * K + hc] : zero4;
        hB = (r1 < N) ? *(const float4*)&H[(size_t)r1 * K + hc] : zero4;
        wA = *(const float4*)&W[(size_t)wk * 64 + wc];
        wB = *(const float4*)&W[(size_t)(wk + 16) * 64 + wc];
    }

    float acc[4][4];
#pragma unroll
    for (int i = 0; i < 4; ++i)
#pragma unroll
        for (int m = 0; m < 4; ++m) acc[i][m] = 0.0f;

    for (int c = 0; c < NCH; ++c) {
        __syncthreads();
        *(float4*)&sH[hr * 36 + hc] = hA;
        *(float4*)&sH[(hr + 32) * 36 + hc] = hB;
        *(float4*)&sW[wk * 64 + wc] = wA;
        *(float4*)&sW[(wk + 16) * 64 + wc] = wB;
        __syncthreads();
        if (c + 1 < NCH) {
            int k0 = (c + 1) * BK;
            int r0 = n0 + hr, r1 = n0 + hr + 32;
            hA = (r0 < N) ? *(const float4*)&H[(size_t)r0 * K + k0 + hc] : zero4;
            hB = (r1 < N) ? *(const float4*)&H[(size_t)r1 * K + k0 + hc] : zero4;
            wA = *(const float4*)&W[(size_t)(k0 + wk) * 64 + wc];
            wB = *(const float4*)&W[(size_t)(k0 + wk + 16) * 64 + wc];
        }
#pragma unroll
        for (int kk = 0; kk < BK; kk += 4) {
            const float4 a0 = *(const float4*)&sH[(4 * ty + 0) * 36 + kk];
            const float4 a1 = *(const float4*)&sH[(4 * ty + 1) * 36 + kk];
            const float4 a2 = *(const float4*)&sH[(4 * ty + 2) * 36 + kk];
            const float4 a3 = *(const float4*)&sH[(4 * ty + 3) * 36 + kk];
            const float4 w0 = *(const float4*)&sW[(kk + 0) * 64 + 4 * tx];
            const float4 w1 = *(const float4*)&sW[(kk + 1) * 64 + 4 * tx];
            const float4 w2 = *(const float4*)&sW[(kk + 2) * 64 + 4 * tx];
            const float4 w3 = *(const float4*)&sW[(kk + 3) * 64 + 4 * tx];
            FMA4(a0.x, w0, 0) FMA4(a1.x, w0, 1) FMA4(a2.x, w0, 2) FMA4(a3.x, w0, 3)
            FMA4(a0.y, w1, 0) FMA4(a1.y, w1, 1) FMA4(a2.y, w1, 2) FMA4(a3.y, w1, 3)
            FMA4(a0.z, w2, 0) FMA4(a1.z, w2, 1) FMA4(a2.z, w2, 2) FMA4(a3.z, w2, 3)
            FMA4(a0.w, w3, 0) FMA4(a1.w, w3, 1) FMA4(a2.w, w3, 2) FMA4(a3.w, w3, 3)
        }
    }

#pragma unroll
    for (int i = 0; i < 4; ++i) {
        int n = n0 + 4 * ty + i;
        if (n < N) {
            float s = norm[n];
            ushort4 o;
            o.x = f2bf(acc[i][0] * s);
            o.y = f2bf(acc[i][1] * s);
            o.z = f2bf(acc[i][2] * s);
            o.w = f2bf(acc[i][3] * s);
            *(ushort4*)&X[(size_t)n * 64 + 4 * tx] = o;
        }
    }
}

// ---------------- segment sum over CSR (bf16 X rows) + fused epilogue ----------------
// 16 lanes per row (uint2 = 4 bf16 each), 4 edges per wave-instruction.
// fl = lane&15 owns features 4fl..4fl+3; eh = lane>>4 owns edge e+eh.
// Butterfly-merge the 4 edge groups at the end; lanes 0-15 write float4.
template<bool ELU>
__global__ __launch_bounds__(256) void segsum_kernel(const unsigned short* __restrict__ X,
                                                     const int* __restrict__ esrc,
                                                     const int* __restrict__ seg,
                                                     const float* __restrict__ norm_dst,
                                                     const float* __restrict__ bias,
                                                     float* __restrict__ out, int N) {
    const int node = blockIdx.x * 4 + (threadIdx.x >> 6);
    const int lane = threadIdx.x & 63;
    if (node >= N) return;
    const int eh = lane >> 4;          // edge slot 0..3
    const int fl = lane & 15;          // feature group
    const int s0 = seg[node];
    const int s1 = seg[node + 1];
    float a0 = 0.0f, a1 = 0.0f, a2 = 0.0f, a3 = 0.0f;
    int e = s0;
    for (; e + 8 <= s1; e += 8) {       // 8 edges: 2 gather instructions
        int r0 = esrc[e + eh];
        int r1 = esrc[e + 4 + eh];
        const uint2 u0 = *(const uint2*)&X[(size_t)r0 * 64 + fl * 4];
        const uint2 u1 = *(const uint2*)&X[(size_t)r1 * 64 + fl * 4];
        a0 += bflo(u0.x); a1 += bfhi(u0.x); a2 += bflo(u0.y); a3 += bfhi(u0.y);
        a0 += bflo(u1.x); a1 += bfhi(u1.x); a2 += bflo(u1.y); a3 += bfhi(u1.y);
    }
    for (; e < s1; e += 4) {            // tail, predicated per edge slot
        int idx = e + eh;
        bool ok = idx < s1;
        int r = esrc[ok ? idx : s0];
        const uint2 u = *(const uint2*)&X[(size_t)r * 64 + fl * 4];
        if (ok) { a0 += bflo(u.x); a1 += bfhi(u.x); a2 += bflo(u.y); a3 += bfhi(u.y); }
    }
    // merge edge slots: xor-16 then xor-32
    a0 += __shfl(a0, lane ^ 16); a1 += __shfl(a1, lane ^ 16);
    a2 += __shfl(a2, lane ^ 16); a3 += __shfl(a3, lane ^ 16);
    a0 += __shfl(a0, lane ^ 32); a1 += __shfl(a1, lane ^ 32);
    a2 += __shfl(a2, lane ^ 32); a3 += __shfl(a3, lane ^ 32);
    if (eh == 0) {
        const float s = norm_dst[node];
        const float4 bb = *(const float4*)&bias[fl * 4];
        float4 r;
        r.x = a0 * s + bb.x;
        r.y = a1 * s + bb.y;
        r.z = a2 * s + bb.z;
        r.w = a3 * s + bb.w;
        if (ELU) {
            r.x = r.x > 0.0f ? r.x : expm1f(r.x);
            r.y = r.y > 0.0f ? r.y : expm1f(r.y);
            r.z = r.z > 0.0f ? r.z : expm1f(r.z);
            r.w = r.w > 0.0f ? r.w : expm1f(r.w);
        }
        *(float4*)&out[(size_t)node * 64 + fl * 4] = r;
    }
}

extern "C" void kernel_launch(void* const* d_in, const int* in_sizes, int n_in,
                              void* d_out, int out_size, void* d_ws, size_t ws_size,
                              hipStream_t stream) {
    const float* h   = (const float*)d_in[0];
    const int*   src = (const int*)d_in[1];
    const int*   dst = (const int*)d_in[2];
    const float* W1  = (const float*)d_in[3];
    const float* b1  = (const float*)d_in[4];
    const float* W2  = (const float*)d_in[5];
    const float* b2  = (const float*)d_in[6];
    float* out = (float*)d_out;

    const int N = in_sizes[0] / 128;       // 100000
    const int E = in_sizes[1];             // 1600000
    const int nbuk = (N + 511) >> 9;       // 196
    const int B1 = (E + CH - 1) / CH;      // 391
    const int M = 2 * nbuk * B1;

    int* iw = (int*)d_ws;
    int* mat   = iw;
    int* scanb = mat + M;
    int* bsums = scanb + M + 4;
    int* pedge = bsums + 256;              // 2E
    int* esrc  = pedge + 2 * (size_t)E;    // E
    int* seg   = esrc + (size_t)E;         // N+1 (+pad)
    float* fw       = (float*)(seg + (size_t)N + 4);
    float* norm_src = fw;
    float* norm_dst = fw + (size_t)N;
    float* H1       = fw + 2 * (size_t)N;              // 64N floats
    unsigned short* Xb = (unsigned short*)(H1 + 64 * (size_t)N);  // 64N bf16

    // ---- CSR build ----
    p1a_kernel<<<B1, 256, 0, stream>>>(src, dst, mat, E, B1, nbuk);
    const int G = (M + 1023) / 1024;
    scan1_kernel<<<G, 256, 0, stream>>>(mat, scanb, bsums, M);
    scan2_kernel<<<1, 256, 0, stream>>>(bsums, scanb, M, G);
    scan3_kernel<<<G, 256, 0, stream>>>(scanb, bsums, M);
    p1c_kernel<<<B1, 256, 0, stream>>>(src, dst, scanb, pedge, E, B1, nbuk);
    p2_kernel<<<nbuk, 256, 0, stream>>>(pedge, scanb, esrc, seg, norm_dst, N, E, B1);
    s2_kernel<<<nbuk, 256, 0, stream>>>(pedge, scanb, norm_src, N, B1, nbuk);

    const int segGrid = (N + 3) / 4;

    // ---- layer 1 ----
    gemm_norm<128><<<(N + 63) / 64, 256, 0, stream>>>(h, W1, norm_src, Xb, N);
    segsum_kernel<true><<<segGrid, 256, 0, stream>>>(Xb, esrc, seg, norm_dst, b1, H1, N);

    // ---- layer 2 ----
    gemm_norm<64><<<(N + 63) / 64, 256, 0, stream>>>(H1, W2, norm_src, Xb, N);
    segsum_kernel<false><<<segGrid, 256, 0, stream>>>(Xb, esrc, seg, norm_dst, b2, out, N);
}

// Round 9
// 317.232 us; speedup vs baseline: 1.4381x; 1.0462x over previous
//
#include <hip/hip_runtime.h>
#include <math.h>

#define CH 4096        // edges per partition block
#define NBUK_MAX 256   // max buckets (N <= 131072)
#define MAXB 12288     // max edges per bucket staged in LDS (48 KB)
#define SRC_BITS 17    // N < 131072 fits in 17 bits

typedef short bf16x8 __attribute__((ext_vector_type(8)));
typedef float f32x4 __attribute__((ext_vector_type(4)));

// bf16 <-> f32 helpers (RNE pack; exact unpack)
__device__ __forceinline__ unsigned short f2bf(float f) {
    union { float f; unsigned int u; } v; v.f = f;
    unsigned int r = (v.u + 0x7FFFu + ((v.u >> 16) & 1u)) >> 16;
    return (unsigned short)r;
}
__device__ __forceinline__ float bf2f(unsigned short u) {
    union { unsigned int u; float f; } v; v.u = ((unsigned int)u) << 16;
    return v.f;
}
// unpack packed pair (low ushort = even feature, high = odd)
__device__ __forceinline__ float bflo(unsigned int u) {
    union { unsigned int u; float f; } v; v.u = u << 16;
    return v.f;
}
__device__ __forceinline__ float bfhi(unsigned int u) {
    union { unsigned int u; float f; } v; v.u = u & 0xFFFF0000u;
    return v.f;
}

// ---------------- P1a: per-block bucket histograms ----------------
__global__ __launch_bounds__(256) void p1a_kernel(const int* __restrict__ src, const int* __restrict__ dst,
                                                  int* __restrict__ mat, int E, int B1, int nbuk) {
    __shared__ int hd[NBUK_MAX], hs[NBUK_MAX];
    const int t = threadIdx.x;
    if (t < nbuk) { hd[t] = 0; hs[t] = 0; }
    __syncthreads();
    const int base = blockIdx.x * CH;
    const int cnt = min(CH, E - base);
    for (int k = t; k < cnt; k += 256) {
        int d = dst[base + k];
        int s = src[base + k];
        atomicAdd(&hd[d >> 9], 1);
        atomicAdd(&hs[s >> 9], 1);
    }
    __syncthreads();
    if (t < nbuk) {
        mat[t * B1 + blockIdx.x] = hd[t];
        mat[(nbuk + t) * B1 + blockIdx.x] = hs[t];
    }
}

// ---------------- 3-phase exclusive scan ----------------
__global__ __launch_bounds__(256) void scan1_kernel(const int* __restrict__ cnt,
                                                    int* __restrict__ seg,
                                                    int* __restrict__ bsums, int N) {
    __shared__ int tsum[256];
    const int t = threadIdx.x;
    const int base = blockIdx.x * 1024 + t * 4;
    int v0 = (base + 0 < N) ? cnt[base + 0] : 0;
    int v1 = (base + 1 < N) ? cnt[base + 1] : 0;
    int v2 = (base + 2 < N) ? cnt[base + 2] : 0;
    int v3 = (base + 3 < N) ? cnt[base + 3] : 0;
    tsum[t] = v0 + v1 + v2 + v3;
    __syncthreads();
    for (int off = 1; off < 256; off <<= 1) {
        int x = (t >= off) ? tsum[t - off] : 0;
        __syncthreads();
        if (t >= off) tsum[t] += x;
        __syncthreads();
    }
    int run = (t > 0) ? tsum[t - 1] : 0;
    if (base + 0 < N) seg[base + 0] = run; run += v0;
    if (base + 1 < N) seg[base + 1] = run; run += v1;
    if (base + 2 < N) seg[base + 2] = run; run += v2;
    if (base + 3 < N) seg[base + 3] = run;
    if (t == 255) bsums[blockIdx.x] = tsum[255];
}

__global__ void scan2_kernel(int* __restrict__ bsums, int* __restrict__ seg, int N, int G) {
    __shared__ int s[256];
    int t = threadIdx.x;
    if (t < G) s[t] = bsums[t];
    __syncthreads();
    if (t == 0) {
        int run = 0;
        for (int i = 0; i < G; ++i) { int v = s[i]; s[i] = run; run += v; }
        seg[N] = run;
    }
    __syncthreads();
    if (t < G) bsums[t] = s[t];
}

__global__ __launch_bounds__(256) void scan3_kernel(int* __restrict__ seg,
                                                    const int* __restrict__ bsums, int N) {
    int add = bsums[blockIdx.x];
    int base = blockIdx.x * 1024 + threadIdx.x * 4;
#pragma unroll
    for (int i = 0; i < 4; ++i) {
        int idx = base + i;
        if (idx < N) seg[idx] += add;
    }
}

// ---------------- P1c: LDS-staged partition scatter ----------------
__global__ __launch_bounds__(256) void p1c_kernel(const int* __restrict__ src, const int* __restrict__ dst,
                                                  const int* __restrict__ scan,
                                                  int* __restrict__ pedge,
                                                  int E, int B1, int nbuk) {
    __shared__ int hd[NBUK_MAX], hs[NBUK_MAX];
    __shared__ int curD[NBUK_MAX], curS[NBUK_MAX];
    __shared__ int baseD[NBUK_MAX], baseS[NBUK_MAX];
    __shared__ int stD[CH];
    __shared__ int stS[CH];
    const int t = threadIdx.x;
    if (t < nbuk) { hd[t] = 0; hs[t] = 0; }
    __syncthreads();
    const int base = blockIdx.x * CH;
    const int cnt = min(CH, E - base);
    int dl[CH / 256], sl[CH / 256];
#pragma unroll
    for (int k = 0; k < CH / 256; ++k) {
        int i = t + k * 256;
        if (i < cnt) {
            dl[k] = dst[base + i];
            sl[k] = src[base + i];
            atomicAdd(&hd[dl[k] >> 9], 1);
            atomicAdd(&hs[sl[k] >> 9], 1);
        }
    }
    __syncthreads();
    for (int off = 1; off < nbuk; off <<= 1) {
        int v0 = (t >= off && t < nbuk) ? hd[t - off] : 0;
        int w0 = (t >= off && t < nbuk) ? hs[t - off] : 0;
        __syncthreads();
        if (t < nbuk) { hd[t] += v0; hs[t] += w0; }
        __syncthreads();
    }
    if (t < nbuk) {
        int excD = t ? hd[t - 1] : 0;
        int excS = t ? hs[t - 1] : 0;
        curD[t] = excD;
        curS[t] = excS;
        baseD[t] = scan[t * B1 + blockIdx.x] - excD;
        baseS[t] = scan[(nbuk + t) * B1 + blockIdx.x] - excS;
    }
    __syncthreads();
#pragma unroll
    for (int k = 0; k < CH / 256; ++k) {
        int i = t + k * 256;
        if (i < cnt) {
            int j = dl[k] >> 9;
            int p = atomicAdd(&curD[j], 1);
            stD[p] = ((dl[k] & 511) << SRC_BITS) | sl[k];
            int jq = sl[k] >> 9;
            int q = atomicAdd(&curS[jq], 1);
            stS[q] = sl[k];
        }
    }
    __syncthreads();
    for (int i = t; i < cnt; i += 256) {
        int lo = 0, hi = nbuk - 1;
        while (lo < hi) { int mid = (lo + hi) >> 1; if (hd[mid] > i) hi = mid; else lo = mid + 1; }
        pedge[baseD[lo] + i] = stD[i];
        int lo2 = 0, hi2 = nbuk - 1;
        while (lo2 < hi2) { int mid = (lo2 + hi2) >> 1; if (hs[mid] > i) hi2 = mid; else lo2 = mid + 1; }
        pedge[baseS[lo2] + i] = stS[i];
    }
}

// ---------------- P2: per-bucket local sort -> esrc, seg, norm_dst ----------------
__global__ __launch_bounds__(256) void p2_kernel(const int* __restrict__ pedge,
                                                 const int* __restrict__ scan,
                                                 int* __restrict__ esrc, int* __restrict__ seg,
                                                 float* __restrict__ norm_dst,
                                                 int N, int E, int B1) {
    __shared__ int h[512];
    __shared__ int cur[512];
    __shared__ int stage[MAXB];
    const int t = threadIdx.x;
    const int b = blockIdx.x;
    h[t] = 0; h[t + 256] = 0;
    __syncthreads();
    const int bb0 = scan[b * B1];
    const int bb1 = scan[(b + 1) * B1];
    for (int i = bb0 + t; i < bb1; i += 256) atomicAdd(&h[(pedge[i] >> SRC_BITS) & 511], 1);
    __syncthreads();
    for (int off = 1; off < 512; off <<= 1) {
        int v0 = (t >= off) ? h[t - off] : 0;
        int v1 = (t + 256 >= off) ? h[t + 256 - off] : 0;
        __syncthreads();
        h[t] += v0;
        h[t + 256] += v1;
        __syncthreads();
    }
#pragma unroll
    for (int r = 0; r < 2; ++r) {
        int j = t + r * 256;
        int exc = j ? h[j - 1] : 0;
        cur[j] = exc;
        int n = (b << 9) + j;
        if (n < N) {
            seg[n] = bb0 + exc;
            norm_dst[n] = rsqrtf(fmaxf((float)(h[j] - exc), 1.0f));
        }
    }
    if (b == 0 && t == 0) seg[N] = E;
    __syncthreads();
    const int cnt = bb1 - bb0;
    for (int i = bb0 + t; i < bb1; i += 256) {
        int v = pedge[i];
        int j = (v >> SRC_BITS) & 511;
        int p = atomicAdd(&cur[j], 1);
        int s = v & ((1 << SRC_BITS) - 1);
        if (p < MAXB) stage[p] = s; else esrc[bb0 + p] = s;
    }
    __syncthreads();
    for (int i = t; i < cnt && i < MAXB; i += 256) esrc[bb0 + i] = stage[i];
}

// ---------------- S2: per-bucket src histogram -> norm_src ----------------
__global__ __launch_bounds__(256) void s2_kernel(const int* __restrict__ pedge, const int* __restrict__ scan,
                                                 float* __restrict__ norm_src, int N, int B1, int nbuk) {
    __shared__ int h[512];
    const int t = threadIdx.x;
    const int b = blockIdx.x;
    h[t] = 0; h[t + 256] = 0;
    __syncthreads();
    const int sb0 = scan[(nbuk + b) * B1];
    const int sb1 = scan[(nbuk + b + 1) * B1];
    for (int i = sb0 + t; i < sb1; i += 256) atomicAdd(&h[pedge[i] & 511], 1);
    __syncthreads();
#pragma unroll
    for (int r = 0; r < 2; ++r) {
        int j = t + r * 256;
        int n = (b << 9) + j;
        if (n < N) norm_src[n] = rsqrtf(fmaxf((float)h[j], 1.0f));
    }
}

// ---------------- X(bf16) = (H @ W) * norm_row  — MFMA split-bf16 ----------------
// 64 nodes x 64 cols per block, 4 waves, wave = 16 nodes (full N).
// A (H rows) loaded straight from global (coalesced 128 B/row/chunk), split
// hi/lo in registers. W staged once per block in LDS, transposed bf16 hi/lo,
// stride K+8 halves (bank-conflict-free b128 frag reads). Product computed as
// Ahi*Bhi + Ahi*Blo + Alo*Bhi (fp32 acc) => fp32-level accuracy.
// Layouts (verified, learn_hip m89/m91): A/B frag [m|n=lane&15][k=quad*8+j],
// D col=lane&15, row=quad*4+reg.
template<int K>
__global__ __launch_bounds__(256) void gemm_norm(const float* __restrict__ H,
                                                 const float* __restrict__ W,
                                                 const float* __restrict__ norm,
                                                 unsigned short* __restrict__ X, int N) {
    constexpr int KP = K + 8;  // padded stride (halves)
    __shared__ __align__(16) unsigned short sHi[64 * KP];
    __shared__ __align__(16) unsigned short sLo[64 * KP];
    const int tid = threadIdx.x;

    // stage W (row-major [K][64]) transposed, split hi/lo
    for (int idx = tid; idx < K * 64; idx += 256) {
        int k = idx >> 6;
        int c = idx & 63;
        float v = W[idx];
        unsigned short hi = f2bf(v);
        sHi[c * KP + k] = hi;
        sLo[c * KP + k] = f2bf(v - bf2f(hi));
    }
    __syncthreads();

    const int w = tid >> 6;
    const int lane = tid & 63;
    const int quad = lane >> 4;
    const int l16 = lane & 15;
    const int n0 = blockIdx.x * 64;
    const int arow = n0 + w * 16 + l16;
    const int arow_c = (arow < N) ? arow : (N - 1);
    const float* Hrow = H + (size_t)arow_c * K + quad * 8;

    f32x4 acc[4];
#pragma unroll
    for (int t = 0; t < 4; ++t) acc[t] = (f32x4){0.0f, 0.0f, 0.0f, 0.0f};

    float4 p0 = *(const float4*)(Hrow + 0);
    float4 p1 = *(const float4*)(Hrow + 4);

#pragma unroll
    for (int kc = 0; kc < K / 32; ++kc) {
        const float v[8] = {p0.x, p0.y, p0.z, p0.w, p1.x, p1.y, p1.z, p1.w};
        bf16x8 aHi, aLo;
#pragma unroll
        for (int j = 0; j < 8; ++j) {
            unsigned short hi = f2bf(v[j]);
            aHi[j] = (short)hi;
            aLo[j] = (short)f2bf(v[j] - bf2f(hi));
        }
        if (kc + 1 < K / 32) {
            p0 = *(const float4*)(Hrow + (kc + 1) * 32 + 0);
            p1 = *(const float4*)(Hrow + (kc + 1) * 32 + 4);
        }
        const int kbase = kc * 32 + quad * 8;
#pragma unroll
        for (int t = 0; t < 4; ++t) {
            const int col = t * 16 + l16;
            const bf16x8 bHi = *(const bf16x8*)&sHi[col * KP + kbase];
            const bf16x8 bLo = *(const bf16x8*)&sLo[col * KP + kbase];
            acc[t] = __builtin_amdgcn_mfma_f32_16x16x32_bf16(aLo, bHi, acc[t], 0, 0, 0);
            acc[t] = __builtin_amdgcn_mfma_f32_16x16x32_bf16(aHi, bLo, acc[t], 0, 0, 0);
            acc[t] = __builtin_amdgcn_mfma_f32_16x16x32_bf16(aHi, bHi, acc[t], 0, 0, 0);
        }
    }

#pragma unroll
    for (int r = 0; r < 4; ++r) {
        const int node = n0 + w * 16 + quad * 4 + r;
        if (node < N) {
            const float s = norm[node];
#pragma unroll
            for (int t = 0; t < 4; ++t) {
                X[(size_t)node * 64 + t * 16 + l16] = f2bf(acc[t][r] * s);
            }
        }
    }
}

// ---------------- segment sum over CSR (bf16 X rows) + fused epilogue ----------------
// 16 lanes per row (uint2 = 4 bf16 each), 4 edges per wave-instruction.
template<bool ELU>
__global__ __launch_bounds__(256) void segsum_kernel(const unsigned short* __restrict__ X,
                                                     const int* __restrict__ esrc,
                                                     const int* __restrict__ seg,
                                                     const float* __restrict__ norm_dst,
                                                     const float* __restrict__ bias,
                                                     float* __restrict__ out, int N) {
    const int node = blockIdx.x * 4 + (threadIdx.x >> 6);
    const int lane = threadIdx.x & 63;
    if (node >= N) return;
    const int eh = lane >> 4;          // edge slot 0..3
    const int fl = lane & 15;          // feature group
    const int s0 = seg[node];
    const int s1 = seg[node + 1];
    float a0 = 0.0f, a1 = 0.0f, a2 = 0.0f, a3 = 0.0f;
    int e = s0;
    for (; e + 8 <= s1; e += 8) {
        int r0 = esrc[e + eh];
        int r1 = esrc[e + 4 + eh];
        const uint2 u0 = *(const uint2*)&X[(size_t)r0 * 64 + fl * 4];
        const uint2 u1 = *(const uint2*)&X[(size_t)r1 * 64 + fl * 4];
        a0 += bflo(u0.x); a1 += bfhi(u0.x); a2 += bflo(u0.y); a3 += bfhi(u0.y);
        a0 += bflo(u1.x); a1 += bfhi(u1.x); a2 += bflo(u1.y); a3 += bfhi(u1.y);
    }
    for (; e < s1; e += 4) {
        int idx = e + eh;
        bool ok = idx < s1;
        int r = esrc[ok ? idx : s0];
        const uint2 u = *(const uint2*)&X[(size_t)r * 64 + fl * 4];
        if (ok) { a0 += bflo(u.x); a1 += bfhi(u.x); a2 += bflo(u.y); a3 += bfhi(u.y); }
    }
    a0 += __shfl(a0, lane ^ 16); a1 += __shfl(a1, lane ^ 16);
    a2 += __shfl(a2, lane ^ 16); a3 += __shfl(a3, lane ^ 16);
    a0 += __shfl(a0, lane ^ 32); a1 += __shfl(a1, lane ^ 32);
    a2 += __shfl(a2, lane ^ 32); a3 += __shfl(a3, lane ^ 32);
    if (eh == 0) {
        const float s = norm_dst[node];
        const float4 bb = *(const float4*)&bias[fl * 4];
        float4 r;
        r.x = a0 * s + bb.x;
        r.y = a1 * s + bb.y;
        r.z = a2 * s + bb.z;
        r.w = a3 * s + bb.w;
        if (ELU) {
            r.x = r.x > 0.0f ? r.x : expm1f(r.x);
            r.y = r.y > 0.0f ? r.y : expm1f(r.y);
            r.z = r.z > 0.0f ? r.z : expm1f(r.z);
            r.w = r.w > 0.0f ? r.w : expm1f(r.w);
        }
        *(float4*)&out[(size_t)node * 64 + fl * 4] = r;
    }
}

extern "C" void kernel_launch(void* const* d_in, const int* in_sizes, int n_in,
                              void* d_out, int out_size, void* d_ws, size_t ws_size,
                              hipStream_t stream) {
    const float* h   = (const float*)d_in[0];
    const int*   src = (const int*)d_in[1];
    const int*   dst = (const int*)d_in[2];
    const float* W1  = (const float*)d_in[3];
    const float* b1  = (const float*)d_in[4];
    const float* W2  = (const float*)d_in[5];
    const float* b2  = (const float*)d_in[6];
    float* out = (float*)d_out;

    const int N = in_sizes[0] / 128;       // 100000
    const int E = in_sizes[1];             // 1600000
    const int nbuk = (N + 511) >> 9;       // 196
    const int B1 = (E + CH - 1) / CH;      // 391
    const int M = 2 * nbuk * B1;

    int* iw = (int*)d_ws;
    int* mat   = iw;
    int* scanb = mat + M;
    int* bsums = scanb + M + 4;
    int* pedge = bsums + 256;              // 2E
    int* esrc  = pedge + 2 * (size_t)E;    // E
    int* seg   = esrc + (size_t)E;         // N+1 (+pad)
    float* fw       = (float*)(seg + (size_t)N + 4);
    float* norm_src = fw;
    float* norm_dst = fw + (size_t)N;
    float* H1       = fw + 2 * (size_t)N;              // 64N floats
    unsigned short* Xb = (unsigned short*)(H1 + 64 * (size_t)N);  // 64N bf16

    // ---- CSR build ----
    p1a_kernel<<<B1, 256, 0, stream>>>(src, dst, mat, E, B1, nbuk);
    const int G = (M + 1023) / 1024;
    scan1_kernel<<<G, 256, 0, stream>>>(mat, scanb, bsums, M);
    scan2_kernel<<<1, 256, 0, stream>>>(bsums, scanb, M, G);
    scan3_kernel<<<G, 256, 0, stream>>>(scanb, bsums, M);
    p1c_kernel<<<B1, 256, 0, stream>>>(src, dst, scanb, pedge, E, B1, nbuk);
    p2_kernel<<<nbuk, 256, 0, stream>>>(pedge, scanb, esrc, seg, norm_dst, N, E, B1);
    s2_kernel<<<nbuk, 256, 0, stream>>>(pedge, scanb, norm_src, N, B1, nbuk);

    const int segGrid = (N + 3) / 4;

    // ---- layer 1 ----
    gemm_norm<128><<<(N + 63) / 64, 256, 0, stream>>>(h, W1, norm_src, Xb, N);
    segsum_kernel<true><<<segGrid, 256, 0, stream>>>(Xb, esrc, seg, norm_dst, b1, H1, N);

    // ---- layer 2 ----
    gemm_norm<64><<<(N + 63) / 64, 256, 0, stream>>>(H1, W2, norm_src, Xb, N);
    segsum_kernel<false><<<segGrid, 256, 0, stream>>>(Xb, esrc, seg, norm_dst, b2, out, N);
}